// Round 24
// baseline (70874.127 us; speedup 1.0000x reference)
//
#include <hip/hip_runtime.h>
#include <hip/hip_bf16.h>

__device__ inline float geluf(float x){ return 0.5f*x*(1.f + erff(x*0.70710678118654752f)); }
__device__ inline float siluf(float x){ return x/(1.f + expf(-x)); }
__device__ inline float softplusf(float x){ return (x > 20.f) ? x : log1pf(expf(x)); }

static constexpr int Lseq = 2048;
static constexpr int Bsz  = 2;
static constexpr int Dm   = 512;
static constexpr int Di   = 1024;
static constexpr int Nst  = 16;
static constexpr int Rr   = 32;
static constexpr int Hch  = 1024;
static constexpr int Dd   = 256;
static constexpr int TOK  = Bsz*Lseq;

// ---------- GEMM1: AB = x @ ip_w^T + ip_b ----------
__global__ void gemm1_k(const float* x, const float* w, const float* b, float* C)
{
  long idx = (long)blockIdx.x*256 + threadIdx.x;
  if (idx >= (long)TOK*Dm) return;
  int m = (int)(idx >> 9), n = (int)(idx & 511);
  float acc = b[n];
  const float* xr = x + (long)m*Dm;
  const float* wr = w + (long)n*Dm;
  for (int k = 0; k < Dm; k++) acc += xr[k]*wr[k];
  C[idx] = acc;
}

template<bool GELU>
__global__ void rms_k(const float* X, const float* W, float* Y, int rows)
{
  int row = blockIdx.x*64 + threadIdx.x;
  if (row >= rows) return;
  const float* xr = X + (long)row*Dm;
  float s = 0.f;
  for (int j = 0; j < Dm; j++) s += xr[j]*xr[j];
  float sc = rsqrtf(s*(1.f/(float)Dm) + 1e-5f);
  float* yr = Y + (long)row*Dm;
  for (int j = 0; j < Dm; j++){
    float o = xr[j]*sc*W[j];
    if (GELU) o = geluf(o);
    yr[j] = o;
  }
}

template<bool RESID>
__global__ void gemmf_k(const float* A, const float* W, float* C, const float* resid,
                        int M, int N, int K)
{
  long idx = (long)blockIdx.x*256 + threadIdx.x;
  if (idx >= (long)M*N) return;
  int m = (int)(idx / N), n = (int)(idx % N);
  float acc = 0.f;
  const float* a = A + (long)m*K;
  const float* w = W + (long)n*K;
  for (int k = 0; k < K; k++) acc += a[k]*w[k];
  if (RESID) acc += resid[idx];
  C[idx] = acc;
}

// ---------- causal depthwise conv (K=4, pad (3,0), cross-correlation) + silu ----------
__global__ void convf_k(const float* xz, const float* cw, const float* cb, float* u)
{
  long idx = (long)blockIdx.x*256 + threadIdx.x;
  if (idx >= (long)Lseq*Di) return;
  int l = (int)(idx >> 10), d = (int)(idx & 1023);
  float acc = cb[d];
  for (int k = 0; k < 4; k++){
    int lk = l - 3 + k;
    if (lk >= 0) acc += xz[(long)lk*2048 + d]*cw[d*4 + k];
  }
  u[idx] = siluf(acc);
}

__global__ void dtf_k(const float* xd, const float* dtw, const float* dtb, float* xz)
{
  long idx = (long)blockIdx.x*256 + threadIdx.x;
  if (idx >= (long)Lseq*Di) return;
  int l = (int)(idx >> 10), d = (int)(idx & 1023);
  float acc = dtb[d];
  for (int r = 0; r < Rr; r++) acc += xd[(long)l*64 + r]*dtw[d*Rr + r];
  xz[(long)l*2048 + d] = softplusf(acc);
}

__global__ void scanf_k(const float* xz, float* u, const float* xd,
                        const float* Alog, const float* Dp)
{
  int d = blockIdx.x*64 + threadIdx.x;
  if (d >= Di) return;
  float An[Nst], h[Nst];
  for (int n = 0; n < Nst; n++){ An[n] = -expf(Alog[d*Nst + n]); h[n] = 0.f; }
  const float Dv = Dp[d];
  for (int t = 0; t < Lseq; t++){
    float dtv = xz[(long)t*2048 + d];
    float uv  = u[(long)t*1024 + d];
    float du  = dtv*uv, acc = 0.f;
    for (int n = 0; n < Nst; n++){
      h[n] = expf(dtv*An[n])*h[n] + du*xd[(long)t*64 + 32 + n];
      acc += h[n]*xd[(long)t*64 + 48 + n];
    }
    float y = acc + uv*Dv;
    u[(long)t*1024 + d] = y * siluf(xz[(long)t*2048 + 1024 + d]);
  }
}

// ---------- temporal conv: (H,Dm,3) weights, pad (1,1), cross-correlation ----------
__global__ void tconvA_k(const float* H, const float* w, const float* bias, float* HC)
{
  long idx = (long)blockIdx.x*256 + threadIdx.x;
  if (idx >= (long)TOK*Hch) return;
  int token = (int)(idx >> 10), o = (int)(idx & 1023);
  int b = token >> 11, l = token & (Lseq-1);
  float acc = bias[o];
  for (int k = 0; k < 3; k++){
    int lk = l - 1 + k;
    if (lk < 0 || lk >= Lseq) continue;
    const float* hr = H + ((long)(b*Lseq + lk))*Dm;
    const float* wr = w + (long)o*(Dm*3) + k;
    for (int c = 0; c < Dm; c++) acc += hr[c]*wr[c*3];
  }
  HC[idx] = acc;
}

__global__ void stats_k(const float* hc, float* S)
{
  int ch = blockIdx.x*256 + threadIdx.x;
  if (ch >= Hch) return;
  float s = 0.f, sq = 0.f;
  for (int r = 0; r < TOK; r++){
    float v = hc[(long)r*Hch + ch];
    s += v; sq += v*v;
  }
  S[ch] = s; S[Hch + ch] = sq;
}

__global__ void normgelu_k(float* HC, const float* S, const float* g, const float* bb)
{
  long idx = (long)blockIdx.x*256 + threadIdx.x;
  if (idx >= (long)TOK*Hch) return;
  int c = (int)(idx & 1023);
  float mu  = S[c]*(1.f/(float)TOK);
  float var = S[Hch + c]*(1.f/(float)TOK) - mu*mu;
  HC[idx] = geluf((HC[idx] - mu)*rsqrtf(var + 1e-5f)*g[c] + bb[c]);
}

// ---------- final GEMM -> FP32 output (the 23-round bug: out is fp32, not bf16) ----------
__global__ void final_k(const float* G, const float* fpw, const float* fpb, float* out)
{
  long idx = (long)blockIdx.x*256 + threadIdx.x;
  if (idx >= (long)TOK*Dd) return;
  int m = (int)(idx >> 8), d = (int)(idx & 255);
  float acc = fpb[d];
  const float* gr = G + (long)m*Hch;
  const float* w = fpw + (long)d*Hch;
  for (int c = 0; c < Hch; c++) acc += gr[c]*w[c];
  out[idx] = acc;
}

__global__ void dummy_k(float* buf, int tag)
{
  if (threadIdx.x == 0 && blockIdx.x == 0) buf[tag] = (float)(tag + 1);
}

// ---------- launch: clean fp32 pipeline, FP32 output ----------
extern "C" void kernel_launch(void* const* d_in, const int* in_sizes, int n_in,
                              void* d_out, int out_size, void* d_ws, size_t ws_size,
                              hipStream_t stream)
{
  const float* x      = (const float*)d_in[0];
  const float* ip_w   = (const float*)d_in[1];
  const float* ip_b   = (const float*)d_in[2];
  const float* ip_nw  = (const float*)d_in[3];
  const float* blk_nw = (const float*)d_in[4];
  const float* in_pw  = (const float*)d_in[5];
  const float* conv_w = (const float*)d_in[6];
  const float* conv_b = (const float*)d_in[7];
  const float* x_pw   = (const float*)d_in[8];
  const float* dt_pw  = (const float*)d_in[9];
  const float* dt_pb  = (const float*)d_in[10];
  const float* A_log  = (const float*)d_in[11];
  const float* Dp     = (const float*)d_in[12];
  const float* out_pw = (const float*)d_in[13];
  const float* tc_w   = (const float*)d_in[14];
  const float* tc_b   = (const float*)d_in[15];
  const float* bn_g   = (const float*)d_in[16];
  const float* bn_b   = (const float*)d_in[17];
  const float* fp_w   = (const float*)d_in[18];
  const float* fp_b   = (const float*)d_in[19];
  float* out = (float*)d_out;          // *** FP32 output buffer ***

  constexpr size_t MB = 1u << 20;
  char* ws = (char*)d_ws;
  float* H    = (float*)(ws);              // [0,8M)   trunk
  float* AB   = (float*)(ws + 8*MB);       // [8,16M)  GEMM1 out
  float* XZb  = (float*)(ws + 8*MB);       // [8,24M)  mamba phase (per-batch)
  float* AB2b = (float*)(ws + 24*MB);      // [24,28M) rmsnorm out
  float* Ub   = (float*)(ws + 24*MB);      // [24,32M)
  float* XDb  = (float*)(ws + 32*MB);      // [32,32.5M)
  float* HC   = (float*)(ws + 8*MB);       // [8,24M)  tconv phase (XZb dead)
  float* S    = (float*)(ws + 24*MB);      // stats
  float* DUM  = (float*)(ws + 33*MB);

  gemm1_k<<<(TOK*Dm + 255)/256, 256, 0, stream>>>(x, ip_w, ip_b, AB);
  rms_k<true><<<TOK/64, 64, 0, stream>>>(AB, ip_nw, H, TOK);

  for (int i = 0; i < 2; i++){
    for (int b = 0; b < Bsz; b++){
      float* Hb = H + (long)b*Lseq*Dm;
      rms_k<false><<<Lseq/64, 64, 0, stream>>>(Hb, blk_nw + i*Dm, AB2b, Lseq);
      gemmf_k<false><<<(Lseq*2*Di + 255)/256, 256, 0, stream>>>(
          AB2b, in_pw + (long)i*2*Di*Dm, XZb, nullptr, Lseq, 2*Di, Dm);
      convf_k<<<(Lseq*Di + 255)/256, 256, 0, stream>>>(
          XZb, conv_w + i*Di*4, conv_b + i*Di, Ub);
      gemmf_k<false><<<(Lseq*64 + 255)/256, 256, 0, stream>>>(
          Ub, x_pw + (long)i*64*Di, XDb, nullptr, Lseq, 64, Di);
      dtf_k<<<(Lseq*Di + 255)/256, 256, 0, stream>>>(
          XDb, dt_pw + (long)i*Di*Rr, dt_pb + i*Di, XZb);
      scanf_k<<<Di/64, 64, 0, stream>>>(
          XZb, Ub, XDb, A_log + (long)i*Di*Nst, Dp + i*Di);
      gemmf_k<true><<<(Lseq*Dm + 255)/256, 256, 0, stream>>>(
          Ub, out_pw + (long)i*Dm*Di, Hb, Hb, Lseq, Dm, Di);
    }
  }

  tconvA_k<<<(TOK*Hch + 255)/256, 256, 0, stream>>>(H, tc_w, tc_b, HC);
  stats_k<<<(Hch + 255)/256, 256, 0, stream>>>(HC, S);
  normgelu_k<<<(TOK*Hch + 255)/256, 256, 0, stream>>>(HC, S, bn_g, bn_b);
  final_k<<<(TOK*Dd + 255)/256, 256, 0, stream>>>(HC, fp_w, fp_b, out);

  for (int t = 0; t < 5; t++)
    dummy_k<<<1, 64, 0, stream>>>(DUM, t);
}